// Round 7
// baseline (94.080 us; speedup 1.0000x reference)
//
#include <hip/hip_runtime.h>

// FUSED single-kernel batched NMS (bit-exact vs the JAX reference), one block
// per batch, ZERO workspace usage (avoids the ~39us/replay d_ws poison-fill
// observed in rocprof and all multi-dispatch overhead).
//
//  A: scores -> LDS, histogram by monotone 11-bit key (2048 buckets)
//  B: per-bucket cnt_gt (suffix sums) -> candidate set = buckets with
//     cnt_gt < kM  (provably a superset of the top-kM, exact under ties)
//  C: stable comparison-rank of ~700 candidates -> top-kM sorted window
//     (canonical boxes + areas + original indices in LDS)
//  D: chunked mask+scan: wave 0 resolves chunk c via ballot fixpoint
//     (R6-proven logic, LDS-resident mask) while waves 1..15 compute
//     chunk c+1's mask rows. Early-exit at max_out kept.
//  E: exact fallbacks (candidate overflow -> full rank; window exhausted ->
//     full rank + serial greedy continuation). Never taken on bench data.
//
// Fallback kernel (round-1, proven) retained for max_out > 512.

constexpr int   kN       = 2048;
constexpr int   kM       = 640;       // sorted window (multiple of 64)
constexpr int   kNCH     = kM / 64;   // 10 chunks
constexpr int   kMW      = kM / 32;   // 20 mask words per row
constexpr int   kMaskPad = 21;        // padded stride (bank-conflict relief)
constexpr int   kCandMax = 1024;
constexpr int   kT       = 1024;      // 16 waves
constexpr float kIouThr  = 0.7f;

__device__ __forceinline__ unsigned scoreKey(float s) {
    // monotone float->uint map; +-0 canonicalized to one key
    const unsigned b = __float_as_uint(s);
    if (s == 0.0f) return 0x80000000u;
    return (b & 0x80000000u) ? ~b : (b | 0x80000000u);
}

__device__ __forceinline__ float4 canonBox(const float4 bx) {
    const float cy1 = fminf(bx.x, bx.z), cy2 = fmaxf(bx.x, bx.z);
    const float cx1 = fminf(bx.y, bx.w), cx2 = fmaxf(bx.y, bx.w);
    return make_float4(cy1, cx1, cy2, cx2);
}

__global__ __launch_bounds__(kT, 1)
void nms_fused(const float* __restrict__ rois,    // [B, kN, 4]
               const float* __restrict__ scores,  // [B, kN]
               float* __restrict__ out,           // [B, max_out, 4]
               int max_out)
{
    const int b    = blockIdx.x;
    const int tid  = threadIdx.x;
    const int lane = tid & 63;
    const int wave = tid >> 6;

    __shared__ float        s_score[kN];                // 8 KB
    __shared__ unsigned     s_hist[kN];                 // 8 KB (-> cnt_gt -> full order)
    __shared__ int          s_wtot[16];
    __shared__ int          s_candIdx[kCandMax];        // 4 KB
    __shared__ int          s_candCount;
    __shared__ float4       s_box[kM];                  // 10 KB canonical, sorted
    __shared__ float        s_area[kM];                 // 2.5 KB
    __shared__ int          s_order[kM];                // 2.5 KB orig idx by rank
    __shared__ unsigned     s_mask[kM][kMaskPad];       // 53.8 KB
    __shared__ unsigned     s_kw[kMW];                  // kept bitmap words
    __shared__ int          s_keep[512];                // kept ORIGINAL indices
    __shared__ float4       s_kbox[512];                // fallback only
    __shared__ float        s_karea[512];
    __shared__ int          s_count, s_stop;

    const float4* rois4 = reinterpret_cast<const float4*>(rois) + (size_t)b * kN;
    const float*  bsc   = scores + (size_t)b * kN;

    // ---- init ----
    for (int i = tid; i < kN; i += kT) s_hist[i] = 0u;
    if (tid < kMW) s_kw[tid] = 0u;
    if (tid == 0) { s_candCount = 0; s_count = 0; s_stop = 0; }
    __syncthreads();

    // ---- A: load + histogram ----
    for (int i = tid; i < kN; i += kT) {
        const float s = bsc[i];
        s_score[i] = s;
        atomicAdd(&s_hist[scoreKey(s) >> 21], 1u);
    }
    __syncthreads();

    // ---- B: cnt_gt per bucket (count of elements in strictly-higher buckets)
    {
        const int b0 = 2 * tid, b1 = 2 * tid + 1;
        const int h0 = (int)s_hist[b0], h1 = (int)s_hist[b1];
        int p = h0 + h1;                                // inclusive lane prefix
        for (int d = 1; d < 64; d <<= 1) {
            const int x = __shfl_up(p, d);
            if (lane >= d) p += x;
        }
        const int wtot = __shfl(p, 63);
        if (lane == 63) s_wtot[wave] = wtot;
        __syncthreads();
        int cross = 0;
        for (int w2 = wave + 1; w2 < 16; ++w2) cross += s_wtot[w2];
        const int cg1 = cross + (wtot - p);             // above bucket b1
        const int cg0 = cg1 + h1;                       // above bucket b0
        __syncthreads();
        s_hist[b0] = (unsigned)cg0; s_hist[b1] = (unsigned)cg1;
        __syncthreads();
    }

    // ---- C: candidate selection + stable rank of candidates ----
    for (int i = tid; i < kN; i += kT) {
        if (s_hist[scoreKey(s_score[i]) >> 21] < (unsigned)kM) {
            const int pos = atomicAdd(&s_candCount, 1);
            if (pos < kCandMax) s_candIdx[pos] = i;
        }
    }
    __syncthreads();
    const int m = s_candCount;

    if (m <= kCandMax) {
        for (int t = tid; t < m; t += kT) {
            const int   i  = s_candIdx[t];
            const float si = s_score[i];
            int rank = 0;
            for (int j = 0; j < m; ++j) {               // broadcast LDS reads
                const int   jj = s_candIdx[j];
                const float sj = s_score[jj];
                rank += (sj > si) || (sj == si && jj < i);
            }
            if (rank < kM) {
                s_order[rank] = i;
                const float4 c = canonBox(rois4[i]);
                s_box[rank]  = c;
                s_area[rank] = (c.z - c.x) * (c.w - c.y);
            }
        }
    } else {
        // overflow (adversarial ties): exact full comparison rank
        for (int i = tid; i < kN; i += kT) {
            const float si = s_score[i];
            int rank = 0;
            for (int j = 0; j < kN; ++j) {
                const float sj = s_score[j];
                rank += (sj > si) || (sj == si && j < i);
            }
            if (rank < kM) {
                s_order[rank] = i;
                const float4 c = canonBox(rois4[i]);
                s_box[rank]  = c;
                s_area[rank] = (c.z - c.x) * (c.w - c.y);
            }
        }
    }
    __syncthreads();

    // ---- D: chunked mask + greedy scan ----
    auto maskRows = [&](int c, int wv, int nw) {
        for (int rr = wv; rr < 64; rr += nw) {
            const int    row = c * 64 + rr;
            const float4 bi  = s_box[row];
            const float  ai  = s_area[row];
            for (int k = 0; k <= c; ++k) {
                const int    j  = k * 64 + lane;
                const float4 bj = s_box[j];
                const float iy1 = fmaxf(bi.x, bj.x);
                const float ix1 = fmaxf(bi.y, bj.y);
                const float iy2 = fminf(bi.z, bj.z);
                const float ix2 = fminf(bi.w, bj.w);
                const float inter = fmaxf(iy2 - iy1, 0.0f) * fmaxf(ix2 - ix1, 0.0f);
                const float uni   = ai + s_area[j] - inter;
                const bool  sup   = (uni > 0.0f) && (inter / uni > kIouThr);
                const unsigned long long bal = __ballot(sup);
                if ((lane >> 1) == k)                   // words 2k, 2k+1
                    s_mask[row][lane] =
                        (lane & 1) ? (unsigned)(bal >> 32) : (unsigned)bal;
            }
        }
    };

    maskRows(0, wave, 16);
    __syncthreads();

    for (int c = 0; c < kNCH; ++c) {
        if (wave == 0) {
            // resolve chunk c (R6-proven ballot fixpoint, LDS-resident)
            const int row = c * 64 + lane;
            unsigned acc = 0u;
            for (int w = 0; w < 2 * c; ++w) acc |= s_mask[row][w] & s_kw[w];
            const unsigned long long prev64 = __ballot(acc != 0u);
            const unsigned long long mycol =
                (unsigned long long)s_mask[row][2 * c] |
                ((unsigned long long)s_mask[row][2 * c + 1] << 32);
            unsigned long long notSup = ~prev64, todo = ~0ull, kept = 0ull;
            int count = s_count;
            while (count < max_out) {
                const unsigned long long cand = notSup & todo;
                if (!cand) break;
                const int u = __builtin_ctzll(cand);    // lowest undecided = KEPT
                if (lane == 0) s_keep[count] = s_order[c * 64 + u];
                ++count;
                kept |= (1ull << u);
                const unsigned long long low =
                    (u == 63) ? ~0ull : ((1ull << (u + 1)) - 1ull);
                todo &= ~low;
                const unsigned long long supByU = __ballot((mycol >> u) & 1ull);
                notSup &= ~(supByU & ~low);             // suppress rows > u only
            }
            if (lane == 0) {
                s_kw[2 * c]     = (unsigned)kept;
                s_kw[2 * c + 1] = (unsigned)(kept >> 32);
                s_count = count;
                if (count >= max_out) s_stop = 1;
            }
        } else if (c + 1 < kNCH) {
            maskRows(c + 1, wave - 1, 15);              // overlap next chunk
        }
        __syncthreads();
        const int stop = s_stop;
        __syncthreads();                                // read before next write
        if (stop) break;
    }

    // ---- E: exact lazy continuation past the window (never on bench data)
    if (s_count < max_out) {
        int* s_ford = (int*)s_hist;                     // full order, reuse LDS
        for (int i = tid; i < kN; i += kT) {
            const float si = s_score[i];
            int rank = 0;
            for (int j = 0; j < kN; ++j) {
                const float sj = s_score[j];
                rank += (sj > si) || (sj == si && j < i);
            }
            s_ford[rank] = i;
        }
        __syncthreads();
        for (int k = tid; k < s_count; k += kT) {
            const float4 c = canonBox(rois4[s_keep[k]]);
            s_kbox[k]  = c;
            s_karea[k] = (c.z - c.x) * (c.w - c.y);
        }
        __syncthreads();
        int count = s_count;
        for (int p = kM; p < kN && count < max_out; ++p) {
            const int    oi = s_ford[p];                // broadcast
            const float4 bi = canonBox(rois4[oi]);
            const float  ai = (bi.z - bi.x) * (bi.w - bi.y);
            bool supb = false;
            for (int k = lane; k < count; k += 64) {    // identical in all waves
                const float4 bk = s_kbox[k];
                const float iy1 = fmaxf(bi.x, bk.x);
                const float ix1 = fmaxf(bi.y, bk.y);
                const float iy2 = fminf(bi.z, bk.z);
                const float ix2 = fminf(bi.w, bk.w);
                const float inter = fmaxf(iy2 - iy1, 0.0f) * fmaxf(ix2 - ix1, 0.0f);
                const float uni   = s_karea[k] + ai - inter;  // f32 add commutes
                supb = supb || ((uni > 0.0f) && (inter / uni > kIouThr));
            }
            if (!__any(supb)) {                         // same result per wave
                if (tid == 0) {
                    s_keep[count]  = oi;
                    s_kbox[count]  = bi;
                    s_karea[count] = ai;
                }
                ++count;
            }
            __syncthreads();
        }
        if (tid == 0) s_count = count;
        __syncthreads();
    }

    // ---- output (pad with original box 0, like the reference) ----
    const int cnt = s_count;
    float4* out4 = reinterpret_cast<float4*>(out) + (size_t)b * max_out;
    for (int c2 = tid; c2 < max_out; c2 += kT) {
        const int oidx = (c2 < cnt) ? s_keep[c2] : 0;
        out4[c2] = rois4[oidx];
    }
}

// ------------------------------------------------- fallback (round-1 kernel)
constexpr int kFbThreads = 1024;

__global__ __launch_bounds__(kFbThreads)
void nms_fallback(const float* __restrict__ rois, const float* __restrict__ scores,
                  float* __restrict__ out, int max_out)
{
    const int b   = blockIdx.x;
    const int tid = threadIdx.x;
    __shared__ float        s_score[kN];
    __shared__ int          s_order[kN];
    __shared__ float4       s_box[kN];
    __shared__ float        s_area[kN];
    __shared__ unsigned int s_sup[kN / 32];
    __shared__ int          s_count;
    const float* brois   = rois   + (size_t)b * kN * 4;
    const float* bscores = scores + (size_t)b * kN;
    for (int i = tid; i < kN; i += kFbThreads) s_score[i] = bscores[i];
    for (int i = tid; i < kN / 32; i += kFbThreads) s_sup[i] = 0u;
    if (tid == 0) s_count = 0;
    __syncthreads();
    for (int i = tid; i < kN; i += kFbThreads) {
        const float si = s_score[i];
        int rank = 0;
        const float4* s4 = reinterpret_cast<const float4*>(s_score);
        for (int j4 = 0; j4 < kN / 4; ++j4) {
            const float4 v = s4[j4];
            const int j = j4 * 4;
            rank += (v.x > si) || (v.x == si && (j + 0) < i);
            rank += (v.y > si) || (v.y == si && (j + 1) < i);
            rank += (v.z > si) || (v.z == si && (j + 2) < i);
            rank += (v.w > si) || (v.w == si && (j + 3) < i);
        }
        s_order[rank] = i;
    }
    __syncthreads();
    for (int r = tid; r < kN; r += kFbThreads) {
        const int idx = s_order[r];
        const float4 bx = *reinterpret_cast<const float4*>(brois + (size_t)idx * 4);
        const float cy1 = fminf(bx.x, bx.z), cy2 = fmaxf(bx.x, bx.z);
        const float cx1 = fminf(bx.y, bx.w), cx2 = fmaxf(bx.y, bx.w);
        s_box[r]  = make_float4(cy1, cx1, cy2, cx2);
        s_area[r] = (cy2 - cy1) * (cx2 - cx1);
    }
    __syncthreads();
    for (int i = 0; i < kN; ++i) {
        const bool sup_i = (s_sup[i >> 5] >> (i & 31)) & 1u;
        if (!sup_i) {
            const float4 bi = s_box[i];
            const float  ai = s_area[i];
            for (int j = i + 1 + tid; j < kN; j += kFbThreads) {
                const float4 bj = s_box[j];
                const float iy1 = fmaxf(bi.x, bj.x);
                const float ix1 = fmaxf(bi.y, bj.y);
                const float iy2 = fminf(bi.z, bj.z);
                const float ix2 = fminf(bi.w, bj.w);
                const float inter = fmaxf(iy2 - iy1, 0.0f) * fmaxf(ix2 - ix1, 0.0f);
                const float uni   = ai + s_area[j] - inter;
                const float iou   = (uni > 0.0f) ? (inter / uni) : 0.0f;
                if (iou > kIouThr) atomicOr(&s_sup[j >> 5], 1u << (j & 31));
            }
            if (tid == 0) {
                const int c = s_count;
                if (c < max_out) {
                    const int oidx = s_order[i];
                    reinterpret_cast<float4*>(out)[(size_t)b * max_out + c] =
                        *reinterpret_cast<const float4*>(brois + (size_t)oidx * 4);
                }
                s_count = c + 1;
            }
        }
        __syncthreads();
        const bool stop = (s_count >= max_out);
        __syncthreads();
        if (stop) break;
    }
    const int c = min(s_count, max_out);
    const float4 pad = *reinterpret_cast<const float4*>(brois);
    for (int r = c + tid; r < max_out; r += kFbThreads) {
        reinterpret_cast<float4*>(out)[(size_t)b * max_out + r] = pad;
    }
}

// ---------------------------------------------------------------- launch
extern "C" void kernel_launch(void* const* d_in, const int* in_sizes, int n_in,
                              void* d_out, int out_size, void* d_ws, size_t ws_size,
                              hipStream_t stream)
{
    const float* rois   = (const float*)d_in[0];
    const float* scores = (const float*)d_in[1];
    float* out = (float*)d_out;

    const int B       = in_sizes[1] / kN;        // scores are [B, kN]
    const int max_out = out_size / (4 * B);      // out is [B, max_out, 4]

    if (max_out <= 512) {
        nms_fused<<<dim3(B), dim3(kT), 0, stream>>>(rois, scores, out, max_out);
    } else {
        nms_fallback<<<dim3(B), dim3(kFbThreads), 0, stream>>>(rois, scores, out, max_out);
    }
}

// Round 8
// 61.121 us; speedup vs baseline: 1.5392x; 1.5392x over previous
//
#include <hip/hip_runtime.h>

// FUSED single-kernel batched NMS (bit-exact vs the JAX reference), one block
// per batch, ZERO workspace usage (R7 confirmed: non-kernel overhead ~2us).
// R8 changes (single-CU work was the R7 cost):
//  - kM 640->448 (scan stops ~row 310; exact fallback E kept as insurance)
//  - mask phase: task=(rowgroup,kblock), bj/aj hoisted to registers per task
//  - candidate rank: u64 key (scoreKey<<32 | ~i), v_readlane broadcast
//    (VALU pipe) instead of per-wave LDS-broadcast m^2 loop
//  - 8192-bucket histogram (13-bit key prefix) to shrink candidate set
//
//  A: scores -> LDS, histogram by monotone 13-bit key prefix (8192 buckets)
//  B: per-bucket cnt_gt via wave+block suffix scan
//  C: candidates = elements whose bucket has cnt_gt < kM (superset of top-kM,
//     exact under ties); stable rank by counting greater u64 keys
//  D: chunked mask+scan: wave 0 resolves chunk c via ballot fixpoint while
//     waves 1..15 compute chunk c+1's mask rows; early-exit at max_out kept
//  E: exact fallbacks (cand overflow -> full rank; window exhausted -> serial
//     greedy continuation). Never taken on bench data.

constexpr int   kN       = 2048;
constexpr int   kM       = 448;       // sorted window (multiple of 64)
constexpr int   kNCH     = kM / 64;   // 7 chunks
constexpr int   kMW      = kM / 32;   // 14 mask words per row
constexpr int   kMaskPad = 15;        // padded stride
constexpr int   kNB      = 8192;      // score buckets
constexpr int   kCandMax = 1024;
constexpr int   kT       = 1024;      // 16 waves
constexpr float kIouThr  = 0.7f;

__device__ __forceinline__ unsigned scoreKey(float s) {
    // monotone float->uint map; +-0 canonicalized to one key
    const unsigned b = __float_as_uint(s);
    if (s == 0.0f) return 0x80000000u;
    return (b & 0x80000000u) ? ~b : (b | 0x80000000u);
}

__device__ __forceinline__ float4 canonBox(const float4 bx) {
    const float cy1 = fminf(bx.x, bx.z), cy2 = fmaxf(bx.x, bx.z);
    const float cx1 = fminf(bx.y, bx.w), cx2 = fmaxf(bx.y, bx.w);
    return make_float4(cy1, cx1, cy2, cx2);
}

__global__ __launch_bounds__(kT, 1)
void nms_fused(const float* __restrict__ rois,    // [B, kN, 4]
               const float* __restrict__ scores,  // [B, kN]
               float* __restrict__ out,           // [B, max_out, 4]
               int max_out)
{
    const int b    = blockIdx.x;
    const int tid  = threadIdx.x;
    const int lane = tid & 63;
    const int wave = tid >> 6;

    __shared__ float                 s_score[kN];            // 8 KB
    __shared__ __align__(16) unsigned s_hist[kNB];           // 32 KB (->cnt_gt; E: order)
    __shared__ int                   s_wtot[16];
    __shared__ unsigned long long    s_candKey[kCandMax];    // 8 KB
    __shared__ int                   s_candIdx[kCandMax];    // 4 KB
    __shared__ int                   s_candCount;
    __shared__ float4                s_box[kM];              // 7 KB canonical sorted
    __shared__ float                 s_area[kM];             // 1.75 KB
    __shared__ int                   s_order[kM];            // 1.75 KB orig idx
    __shared__ unsigned              s_mask[kM][kMaskPad];   // 26.9 KB
    __shared__ unsigned              s_kw[kMW];              // kept bitmap words
    __shared__ int                   s_keep[512];            // kept ORIGINAL indices
    __shared__ float4                s_kbox[512];            // fallback only
    __shared__ float                 s_karea[512];
    __shared__ int                   s_count, s_stop;

    const float4* rois4 = reinterpret_cast<const float4*>(rois) + (size_t)b * kN;
    const float*  bsc   = scores + (size_t)b * kN;

    // ---- init ----
    for (int i = tid; i < kNB; i += kT) s_hist[i] = 0u;
    if (tid < kMW) s_kw[tid] = 0u;
    if (tid == 0) { s_candCount = 0; s_count = 0; s_stop = 0; }
    __syncthreads();

    // ---- A: load + histogram (13-bit key prefix) ----
    for (int i = tid; i < kN; i += kT) {
        const float s = bsc[i];
        s_score[i] = s;
        atomicAdd(&s_hist[scoreKey(s) >> 19], 1u);
    }
    __syncthreads();

    // ---- B: cnt_gt per bucket (elements in strictly-higher buckets) ----
    {
        const int q0 = tid * 8;
        const uint4 hA = *reinterpret_cast<const uint4*>(&s_hist[q0]);
        const uint4 hB = *reinterpret_cast<const uint4*>(&s_hist[q0 + 4]);
        int p = (int)(hA.x + hA.y + hA.z + hA.w + hB.x + hB.y + hB.z + hB.w);
        for (int d = 1; d < 64; d <<= 1) {
            const int x = __shfl_up(p, d);
            if (lane >= d) p += x;
        }
        const int wtot = __shfl(p, 63);
        if (lane == 63) s_wtot[wave] = wtot;
        __syncthreads();
        int above = wtot - p;                       // strictly-above, this wave
        for (int w2 = wave + 1; w2 < 16; ++w2) above += s_wtot[w2];
        const unsigned c7 = (unsigned)above;
        const unsigned c6 = c7 + hB.w;
        const unsigned c5 = c6 + hB.z;
        const unsigned c4 = c5 + hB.y;
        const unsigned c3 = c4 + hB.x;
        const unsigned c2 = c3 + hA.w;
        const unsigned c1 = c2 + hA.z;
        const unsigned c0 = c1 + hA.y;
        __syncthreads();
        *reinterpret_cast<uint4*>(&s_hist[q0])     = make_uint4(c0, c1, c2, c3);
        *reinterpret_cast<uint4*>(&s_hist[q0 + 4]) = make_uint4(c4, c5, c6, c7);
        __syncthreads();
    }

    // ---- C: candidate selection + stable rank via u64 keys ----
    for (int i = tid; i < kN; i += kT) {
        const unsigned key = scoreKey(s_score[i]);
        if (s_hist[key >> 19] < (unsigned)kM) {
            const int pos = atomicAdd(&s_candCount, 1);
            if (pos < kCandMax) {
                s_candIdx[pos] = i;
                // descending score, ascending index: bigger key = earlier
                s_candKey[pos] = ((unsigned long long)key << 32) |
                                 (unsigned)(~(unsigned)i);
            }
        }
    }
    __syncthreads();
    const int m = s_candCount;

    if (m <= kCandMax) {
        const int mPad = (m + 63) & ~63;
        for (int t = m + tid; t < mPad; t += kT) s_candKey[t] = 0ull; // pad < any real
        __syncthreads();
        const int nblk = mPad >> 6;
        for (int t = tid; t < mPad; t += kT) {      // uniform trip per wave
            const unsigned long long myK = s_candKey[t];
            int rank = 0;
            for (int blk = 0; blk < nblk; ++blk) {
                const unsigned long long kj = s_candKey[blk * 64 + lane];
                const int kjLo = (int)(unsigned)kj;
                const int kjHi = (int)(unsigned)(kj >> 32);
#pragma unroll
                for (int q = 0; q < 64; ++q) {      // VALU-pipe broadcast
                    const unsigned lo = (unsigned)__builtin_amdgcn_readlane(kjLo, q);
                    const unsigned hi = (unsigned)__builtin_amdgcn_readlane(kjHi, q);
                    const unsigned long long Kj =
                        ((unsigned long long)hi << 32) | lo;
                    rank += (Kj > myK);
                }
            }
            if (t < m && rank < kM) {
                const int i = s_candIdx[t];
                s_order[rank] = i;
                const float4 c = canonBox(rois4[i]);
                s_box[rank]  = c;
                s_area[rank] = (c.z - c.x) * (c.w - c.y);
            }
        }
    } else {
        // overflow (adversarial ties): exact full comparison rank
        for (int i = tid; i < kN; i += kT) {
            const float si = s_score[i];
            int rank = 0;
            for (int j = 0; j < kN; ++j) {
                const float sj = s_score[j];
                rank += (sj > si) || (sj == si && j < i);
            }
            if (rank < kM) {
                s_order[rank] = i;
                const float4 c = canonBox(rois4[i]);
                s_box[rank]  = c;
                s_area[rank] = (c.z - c.x) * (c.w - c.y);
            }
        }
    }
    __syncthreads();

    // ---- D: chunked mask + greedy scan ----
    // mask row i, word-pair 2k/2k+1 <- IoU(box_i, box_{k*64+lane}) > thr
    auto maskChunk = [&](int cc, int wv, int nw) {
        const int ntask = (cc + 1) * 4;             // (k, rowgroup) tasks
        for (int tsk = wv; tsk < ntask; tsk += nw) {
            const int k  = tsk >> 2;
            const int rg = tsk & 3;
            const float4 bj = s_box[k * 64 + lane]; // hoisted per task
            const float  aj = s_area[k * 64 + lane];
            const int rbase = cc * 64 + rg * 16;
            for (int rr = 0; rr < 16; ++rr) {
                const int    row = rbase + rr;
                const float4 bi  = s_box[row];      // broadcast
                const float iy1 = fmaxf(bi.x, bj.x);
                const float ix1 = fmaxf(bi.y, bj.y);
                const float iy2 = fminf(bi.z, bj.z);
                const float ix2 = fminf(bi.w, bj.w);
                const float inter = fmaxf(iy2 - iy1, 0.0f) * fmaxf(ix2 - ix1, 0.0f);
                const float uni   = s_area[row] + aj - inter;
                const bool  sup   = (uni > 0.0f) && (inter / uni > kIouThr);
                const unsigned long long bal = __ballot(sup);
                if ((lane >> 1) == k)               // lanes 2k, 2k+1 write
                    s_mask[row][lane] =
                        (lane & 1) ? (unsigned)(bal >> 32) : (unsigned)bal;
            }
        }
    };

    maskChunk(0, wave, 16);
    __syncthreads();

    for (int c = 0; c < kNCH; ++c) {
        if (wave == 0) {
            // resolve chunk c (ballot fixpoint; proven R6/R7)
            const int row = c * 64 + lane;
            unsigned acc = 0u;
            for (int w = 0; w < 2 * c; ++w) acc |= s_mask[row][w] & s_kw[w];
            const unsigned long long prev64 = __ballot(acc != 0u);
            const unsigned long long mycol =
                (unsigned long long)s_mask[row][2 * c] |
                ((unsigned long long)s_mask[row][2 * c + 1] << 32);
            unsigned long long notSup = ~prev64, todo = ~0ull, kept = 0ull;
            int count = s_count;
            while (count < max_out) {
                const unsigned long long cand = notSup & todo;
                if (!cand) break;
                const int u = __builtin_ctzll(cand);    // lowest undecided = KEPT
                if (lane == 0) s_keep[count] = s_order[c * 64 + u];
                ++count;
                kept |= (1ull << u);
                const unsigned long long low =
                    (u == 63) ? ~0ull : ((1ull << (u + 1)) - 1ull);
                todo &= ~low;
                const unsigned long long supByU = __ballot((mycol >> u) & 1ull);
                notSup &= ~(supByU & ~low);             // suppress rows > u only
            }
            if (lane == 0) {
                s_kw[2 * c]     = (unsigned)kept;
                s_kw[2 * c + 1] = (unsigned)(kept >> 32);
                s_count = count;
                if (count >= max_out) s_stop = 1;
            }
        } else if (c + 1 < kNCH) {
            maskChunk(c + 1, wave - 1, 15);             // overlap next chunk
        }
        __syncthreads();
        const int stop = s_stop;
        __syncthreads();                                // read before next write
        if (stop) break;
    }

    // ---- E: exact lazy continuation past the window (never on bench data)
    if (s_count < max_out) {
        int* s_ford = (int*)s_hist;                     // full order, reuse LDS
        for (int i = tid; i < kN; i += kT) {
            const float si = s_score[i];
            int rank = 0;
            for (int j = 0; j < kN; ++j) {
                const float sj = s_score[j];
                rank += (sj > si) || (sj == si && j < i);
            }
            s_ford[rank] = i;
        }
        __syncthreads();
        for (int k = tid; k < s_count; k += kT) {
            const float4 c = canonBox(rois4[s_keep[k]]);
            s_kbox[k]  = c;
            s_karea[k] = (c.z - c.x) * (c.w - c.y);
        }
        __syncthreads();
        int count = s_count;
        for (int p = kM; p < kN && count < max_out; ++p) {
            const int    oi = s_ford[p];                // broadcast
            const float4 bi = canonBox(rois4[oi]);
            const float  ai = (bi.z - bi.x) * (bi.w - bi.y);
            bool supb = false;
            for (int k = lane; k < count; k += 64) {    // identical in all waves
                const float4 bk = s_kbox[k];
                const float iy1 = fmaxf(bi.x, bk.x);
                const float ix1 = fmaxf(bi.y, bk.y);
                const float iy2 = fminf(bi.z, bk.z);
                const float ix2 = fminf(bi.w, bk.w);
                const float inter = fmaxf(iy2 - iy1, 0.0f) * fmaxf(ix2 - ix1, 0.0f);
                const float uni   = s_karea[k] + ai - inter;  // f32 add commutes
                supb = supb || ((uni > 0.0f) && (inter / uni > kIouThr));
            }
            if (!__any(supb)) {                         // same result per wave
                if (tid == 0) {
                    s_keep[count]  = oi;
                    s_kbox[count]  = bi;
                    s_karea[count] = ai;
                }
                ++count;
            }
            __syncthreads();
        }
        if (tid == 0) s_count = count;
        __syncthreads();
    }

    // ---- output (pad with original box 0, like the reference) ----
    const int cnt = s_count;
    float4* out4 = reinterpret_cast<float4*>(out) + (size_t)b * max_out;
    for (int c2 = tid; c2 < max_out; c2 += kT) {
        const int oidx = (c2 < cnt) ? s_keep[c2] : 0;
        out4[c2] = rois4[oidx];
    }
}

// ------------------------------------------------- fallback (round-1 kernel)
constexpr int kFbThreads = 1024;

__global__ __launch_bounds__(kFbThreads)
void nms_fallback(const float* __restrict__ rois, const float* __restrict__ scores,
                  float* __restrict__ out, int max_out)
{
    const int b   = blockIdx.x;
    const int tid = threadIdx.x;
    __shared__ float        s_score[kN];
    __shared__ int          s_order[kN];
    __shared__ float4       s_box[kN];
    __shared__ float        s_area[kN];
    __shared__ unsigned int s_sup[kN / 32];
    __shared__ int          s_count;
    const float* brois   = rois   + (size_t)b * kN * 4;
    const float* bscores = scores + (size_t)b * kN;
    for (int i = tid; i < kN; i += kFbThreads) s_score[i] = bscores[i];
    for (int i = tid; i < kN / 32; i += kFbThreads) s_sup[i] = 0u;
    if (tid == 0) s_count = 0;
    __syncthreads();
    for (int i = tid; i < kN; i += kFbThreads) {
        const float si = s_score[i];
        int rank = 0;
        const float4* s4 = reinterpret_cast<const float4*>(s_score);
        for (int j4 = 0; j4 < kN / 4; ++j4) {
            const float4 v = s4[j4];
            const int j = j4 * 4;
            rank += (v.x > si) || (v.x == si && (j + 0) < i);
            rank += (v.y > si) || (v.y == si && (j + 1) < i);
            rank += (v.z > si) || (v.z == si && (j + 2) < i);
            rank += (v.w > si) || (v.w == si && (j + 3) < i);
        }
        s_order[rank] = i;
    }
    __syncthreads();
    for (int r = tid; r < kN; r += kFbThreads) {
        const int idx = s_order[r];
        const float4 bx = *reinterpret_cast<const float4*>(brois + (size_t)idx * 4);
        const float cy1 = fminf(bx.x, bx.z), cy2 = fmaxf(bx.x, bx.z);
        const float cx1 = fminf(bx.y, bx.w), cx2 = fmaxf(bx.y, bx.w);
        s_box[r]  = make_float4(cy1, cx1, cy2, cx2);
        s_area[r] = (cy2 - cy1) * (cx2 - cx1);
    }
    __syncthreads();
    for (int i = 0; i < kN; ++i) {
        const bool sup_i = (s_sup[i >> 5] >> (i & 31)) & 1u;
        if (!sup_i) {
            const float4 bi = s_box[i];
            const float  ai = s_area[i];
            for (int j = i + 1 + tid; j < kN; j += kFbThreads) {
                const float4 bj = s_box[j];
                const float iy1 = fmaxf(bi.x, bj.x);
                const float ix1 = fmaxf(bi.y, bj.y);
                const float iy2 = fminf(bi.z, bj.z);
                const float ix2 = fminf(bi.w, bj.w);
                const float inter = fmaxf(iy2 - iy1, 0.0f) * fmaxf(ix2 - ix1, 0.0f);
                const float uni   = ai + s_area[j] - inter;
                const float iou   = (uni > 0.0f) ? (inter / uni) : 0.0f;
                if (iou > kIouThr) atomicOr(&s_sup[j >> 5], 1u << (j & 31));
            }
            if (tid == 0) {
                const int c = s_count;
                if (c < max_out) {
                    const int oidx = s_order[i];
                    reinterpret_cast<float4*>(out)[(size_t)b * max_out + c] =
                        *reinterpret_cast<const float4*>(brois + (size_t)oidx * 4);
                }
                s_count = c + 1;
            }
        }
        __syncthreads();
        const bool stop = (s_count >= max_out);
        __syncthreads();
        if (stop) break;
    }
    const int c = min(s_count, max_out);
    const float4 pad = *reinterpret_cast<const float4*>(brois);
    for (int r = c + tid; r < max_out; r += kFbThreads) {
        reinterpret_cast<float4*>(out)[(size_t)b * max_out + r] = pad;
    }
}

// ---------------------------------------------------------------- launch
extern "C" void kernel_launch(void* const* d_in, const int* in_sizes, int n_in,
                              void* d_out, int out_size, void* d_ws, size_t ws_size,
                              hipStream_t stream)
{
    const float* rois   = (const float*)d_in[0];
    const float* scores = (const float*)d_in[1];
    float* out = (float*)d_out;

    const int B       = in_sizes[1] / kN;        // scores are [B, kN]
    const int max_out = out_size / (4 * B);      // out is [B, max_out, 4]

    if (max_out <= 512) {
        nms_fused<<<dim3(B), dim3(kT), 0, stream>>>(rois, scores, out, max_out);
    } else {
        nms_fallback<<<dim3(B), dim3(kFbThreads), 0, stream>>>(rois, scores, out, max_out);
    }
}